// Round 17
// baseline (1314.273 us; speedup 1.0000x reference)
//
#include <hip/hip_runtime.h>

typedef unsigned short u16;
typedef unsigned int u32;
typedef short short8 __attribute__((ext_vector_type(8)));
typedef float f32x4 __attribute__((ext_vector_type(4)));

#define DEV static __device__ __forceinline__

DEV u16 f2bf(float f) {
  u32 u = __builtin_bit_cast(u32, f);
  u32 r = u + 0x7FFFu + ((u >> 16) & 1u);
  return (u16)(r >> 16);
}
DEV float bf2f(u16 h) { u32 u = ((u32)h) << 16; return __builtin_bit_cast(float, u); }

DEV u32 cvtpk(float lo, float hi_) {
  u32 r;
  asm("v_cvt_pk_bf16_f32 %0, %1, %2" : "=v"(r) : "v"(lo), "v"(hi_));
  return r;
}

DEV void async16(const u16* g, u16* l) {
  __builtin_amdgcn_global_load_lds((const __attribute__((address_space(1))) void*)g,
                                   (__attribute__((address_space(3))) void*)l, 16, 0, 0);
}

// ---------------- 128-tile bf16 MFMA GEMM (2-phase) — head GEMMs ---------------------
template<bool RELU, bool OUTBF, bool RESID, bool SPLIT3>
__global__ __launch_bounds__(256, 2) void gemm_kernel(
    const u16* __restrict__ A, const u16* __restrict__ A2, int KA,
    int lda, int lda2,
    const u16* __restrict__ Bt, int K,
    const float* __restrict__ bias, const float* __restrict__ resid,
    float* __restrict__ Cf, u16* __restrict__ Cb, u16* __restrict__ Cb2, u16* __restrict__ Cb3,
    int ldc)
{
  __shared__ u16 smem[2][16384];   // [buf][A 8192 | B 8192] = 64 KiB
  const int tid = threadIdx.x, wave = tid >> 6, lane = tid & 63;
  const int m0 = blockIdx.x * 128, n0 = blockIdx.y * 128;
  const int wr = wave >> 1, wc = wave & 1;
  const int lj = lane & 15, hi = lane >> 4;

  f32x4 acc[4][4];
  const f32x4 zz = {0.f, 0.f, 0.f, 0.f};
#pragma unroll
  for (int i = 0; i < 4; i++)
#pragma unroll
    for (int j = 0; j < 4; j++) acc[i][j] = zz;

  const int nkt = K / 64;

  auto stage = [&](int buf, int kt) {
    int kofs = kt * 64;
    const u16* sa; int la;
    if (kofs < KA) { sa = A + kofs; la = lda; }
    else           { sa = A2 + (kofs - KA); la = lda2; }
#pragma unroll
    for (int i = 0; i < 8; i++) {
      int c = wave * 8 + i;
      if (c < 16) {
        const u16* g = sa + (size_t)(m0 + c * 8 + (lane >> 3)) * la + (lane & 7) * 8;
        async16(g, &smem[buf][c * 512]);
      } else {
        const u16* g = Bt + (size_t)(n0 + (c - 16) * 8 + (lane >> 3)) * K + kofs + (lane & 7) * 8;
        async16(g, &smem[buf][c * 512]);
      }
    }
  };

  stage(0, 0);
  int cur = 0;
  for (int kt = 0; kt < nkt; kt++) {
    __syncthreads();
    if (kt + 1 < nkt) stage(cur ^ 1, kt + 1);
    const u16* la_ = &smem[cur][0];
    const u16* lb_ = &smem[cur][8192];
#pragma unroll
    for (int ks = 0; ks < 2; ks++) {
      short8 af[4], bfr[4];
#pragma unroll
      for (int mi = 0; mi < 4; mi++)
        af[mi] = *(const short8*)(la_ + (wr * 64 + mi * 16 + lj) * 64 + ks * 32 + hi * 8);
#pragma unroll
      for (int ni = 0; ni < 4; ni++)
        bfr[ni] = *(const short8*)(lb_ + (wc * 64 + ni * 16 + lj) * 64 + ks * 32 + hi * 8);
#pragma unroll
      for (int mi = 0; mi < 4; mi++)
#pragma unroll
        for (int ni = 0; ni < 4; ni++)
          acc[mi][ni] = __builtin_amdgcn_mfma_f32_16x16x32_bf16(af[mi], bfr[ni], acc[mi][ni], 0, 0, 0);
    }
    cur ^= 1;
  }

  u16* outB = Cb;
  int nloc = n0;
  if (SPLIT3) {
    int sec = n0 >> 9;
    outB = (sec == 0) ? Cb : (sec == 1) ? Cb2 : Cb3;
    nloc = n0 & 511;
  }

  float bv[4];
#pragma unroll
  for (int ni = 0; ni < 4; ni++) bv[ni] = bias[n0 + wc * 64 + ni * 16 + lj];
#pragma unroll
  for (int mi = 0; mi < 4; mi++)
#pragma unroll
    for (int r = 0; r < 4; r++) {
      int row = m0 + wr * 64 + mi * 16 + hi * 4 + r;
      size_t rb = (size_t)row * ldc;
#pragma unroll
      for (int ni = 0; ni < 4; ni++) {
        int col = nloc + wc * 64 + ni * 16 + lj;
        float v = acc[mi][ni][r] + bv[ni];
        if (RESID) v += resid[rb + col];
        if (RELU) v = fmaxf(v, 0.f);
        if (OUTBF) outB[rb + col] = f2bf(v);
        else Cf[rb + col] = v;
      }
    }
}

// ---------------- 256-tile bf16 MFMA GEMM, ONE phase per K-tile — QKV/QK+V/W1 --------
template<bool RELU, bool SPLIT3>
__global__ __launch_bounds__(512) void gemm256_kernel(
    const u16* __restrict__ A, const u16* __restrict__ A2v, int lda,
    const u16* __restrict__ Bt, int K,
    const float* __restrict__ bias,
    u16* __restrict__ Cb, u16* __restrict__ Cb2, u16* __restrict__ Cb3, int ldc)
{
  __shared__ u16 smem[65536];  // A: buf*16384 ; B: 32768 + buf*16384 (elems), 128 KiB
  const int tid = threadIdx.x, wave = tid >> 6, lane = tid & 63;
  const int m0 = blockIdx.x * 256, n0 = blockIdx.y * 256;
  const int wm = wave >> 2, wn = wave & 3;
  const int lj = lane & 15, hi = lane >> 4;
  const int srow = wave * 8 + (lane >> 3);
  const int schunk = (lane & 7) ^ ((lane >> 3) & 7);

  const u16* Asrc = (SPLIT3 && (n0 >> 9) == 2 && A2v) ? A2v : A;

  f32x4 acc[8][4];
  const f32x4 zz = {0.f, 0.f, 0.f, 0.f};
#pragma unroll
  for (int i = 0; i < 8; i++)
#pragma unroll
    for (int j = 0; j < 4; j++) acc[i][j] = zz;

  const int nkt = K / 64;

  auto stageA = [&](int buf, int kt, int seg) {
    const u16* g = Asrc + (size_t)(m0 + seg * 64 + srow) * lda + kt * 64 + schunk * 8;
    async16(g, &smem[buf * 16384 + (seg * 64 + wave * 8) * 64]);
  };
  auto stageB = [&](int buf, int kt, int seg) {
    const u16* g = Bt + (size_t)(n0 + seg * 64 + srow) * K + kt * 64 + schunk * 8;
    async16(g, &smem[32768 + buf * 16384 + (seg * 64 + wave * 8) * 64]);
  };

#pragma unroll
  for (int seg = 0; seg < 4; seg++) stageA(0, 0, seg);
#pragma unroll
  for (int seg = 0; seg < 4; seg++) stageB(0, 0, seg);

  int cur = 0;
  for (int t = 0; t < nkt; t++) {
    const bool pf = (t + 1 < nkt);
    const char* aB = (const char*)smem + cur * 32768;
    const char* bB = (const char*)smem + 65536 + cur * 32768;

    if (pf) {
#pragma unroll
      for (int seg = 0; seg < 4; seg++) stageA(cur ^ 1, t + 1, seg);
#pragma unroll
      for (int seg = 0; seg < 4; seg++) stageB(cur ^ 1, t + 1, seg);
    }
    if (pf) asm volatile("s_waitcnt vmcnt(8)" ::: "memory");
    else    asm volatile("s_waitcnt vmcnt(0)" ::: "memory");
    __builtin_amdgcn_s_barrier();

    short8 bfr[4][2];
#pragma unroll
    for (int ni = 0; ni < 4; ni++) {
      int row = wn * 64 + ni * 16 + lj;
#pragma unroll
      for (int ks = 0; ks < 2; ks++)
        bfr[ni][ks] = *(const short8*)(bB + row * 128 + ((ks * 64 + hi * 16) ^ ((row & 7) << 4)));
    }
#pragma unroll
    for (int mh = 0; mh < 2; mh++) {
      short8 af[4][2];
#pragma unroll
      for (int mi = 0; mi < 4; mi++) {
        int row = wm * 128 + (mh * 4 + mi) * 16 + lj;
#pragma unroll
        for (int ks = 0; ks < 2; ks++)
          af[mi][ks] = *(const short8*)(aB + row * 128 + ((ks * 64 + hi * 16) ^ ((row & 7) << 4)));
      }
      __builtin_amdgcn_s_setprio(1);
#pragma unroll
      for (int mi = 0; mi < 4; mi++)
#pragma unroll
        for (int ni = 0; ni < 4; ni++)
#pragma unroll
          for (int ks = 0; ks < 2; ks++)
            acc[mh * 4 + mi][ni] =
                __builtin_amdgcn_mfma_f32_16x16x32_bf16(af[mi][ks], bfr[ni][ks],
                                                        acc[mh * 4 + mi][ni], 0, 0, 0);
      __builtin_amdgcn_s_setprio(0);
    }
    __builtin_amdgcn_s_barrier();
    cur ^= 1;
  }

  u16* outB = Cb;
  int nloc = n0;
  if (SPLIT3) {
    int sec = n0 >> 9;
    outB = (sec == 0) ? Cb : (sec == 1) ? Cb2 : Cb3;
    nloc = n0 & 511;
  }

  float bv[4];
#pragma unroll
  for (int ni = 0; ni < 4; ni++) bv[ni] = bias[n0 + wn * 64 + ni * 16 + lj];
#pragma unroll
  for (int mi = 0; mi < 8; mi++)
#pragma unroll
    for (int r = 0; r < 4; r++) {
      int row = m0 + wm * 128 + mi * 16 + hi * 4 + r;
      size_t rb = (size_t)row * ldc;
#pragma unroll
      for (int ni = 0; ni < 4; ni++) {
        int col = nloc + wn * 64 + ni * 16 + lj;
        float v = acc[mi][ni][r] + bv[ni];
        if (RELU) v = fmaxf(v, 0.f);
        outB[rb + col] = f2bf(v);
      }
    }
}

// ---------------- fused GEMM + bias + residual + LayerNorm (N=512 full-row tile) -----
// v5: r13 memory structure (144 KiB dbuf LDS, ONE phase per K-tile, counted vmcnt)
// but 1024 threads = 16 waves x 32 cols (acc[4][2], 16 MFMA/tile): 4 waves/SIMD for
// latency hiding. Staging: all threads 4 B-loads; waves 0-7 add 1 A-load
// (wave-uniform vmcnt(5)/vmcnt(4)). STOREF=false skips the dead fp32 output.
template<bool STOREF>
__global__ __launch_bounds__(1024) void gemmln_kernel(
    const u16* __restrict__ A, int lda,
    const u16* __restrict__ Bt, int K,
    const float* __restrict__ bias, const float* __restrict__ resid,
    const float* __restrict__ gamma, const float* __restrict__ beta,
    float* __restrict__ outF, u16* __restrict__ outB)
{
  __shared__ u16 smem[73728];  // A: 2x4096 elems [0,8192) ; B: 2x32768 [8192,73728) = 144 KiB
  const int tid = threadIdx.x, wave = tid >> 6, lane = tid & 63;
  const int m0 = blockIdx.x * 64;
  const int lj = lane & 15, hi = lane >> 4;

  f32x4 acc[4][2];
  const f32x4 zz = {0.f, 0.f, 0.f, 0.f};
#pragma unroll
  for (int i = 0; i < 4; i++)
#pragma unroll
    for (int j = 0; j < 2; j++) acc[i][j] = zz;

  const int nkt = K / 64;

  // A tile 64x64: threads 0-511, one 16B load each. row = tid>>3, chunk = tid&7.
  auto stageA = [&](int buf, int kt) {
    if (tid < 512) {
      int row = tid >> 3, ch = tid & 7;
      int sc = ch ^ (row & 7);
      const u16* g = A + (size_t)(m0 + row) * lda + kt * 64 + sc * 8;
      async16(g, &smem[buf * 4096 + row * 64 + ch * 8]);
    }
  };
  // B panel 512x64: all 1024 threads, 4 loads each. idx = tid + l*1024.
  auto stageB = [&](int buf, int kt) {
#pragma unroll
    for (int l = 0; l < 4; l++) {
      int idx = tid + l * 1024;
      int row = idx >> 3, ch = idx & 7;
      int sc = ch ^ (row & 7);
      const u16* g = Bt + (size_t)row * K + kt * 64 + sc * 8;
      async16(g, &smem[8192 + buf * 32768 + row * 64 + ch * 8]);
    }
  };

  stageA(0, 0);
  stageB(0, 0);

  int cur = 0;
  for (int t = 0; t < nkt; t++) {
    const bool pf = (t + 1 < nkt);
    if (pf) {
      stageA(cur ^ 1, t + 1);
      stageB(cur ^ 1, t + 1);
      if (wave < 8) asm volatile("s_waitcnt vmcnt(5)" ::: "memory");
      else          asm volatile("s_waitcnt vmcnt(4)" ::: "memory");
    } else {
      asm volatile("s_waitcnt vmcnt(0)" ::: "memory");
    }
    __builtin_amdgcn_s_barrier();

    const char* aB = (const char*)smem + cur * 8192;
    const char* bB = (const char*)smem + 16384 + cur * 65536;
    short8 af[4][2], bfr[2][2];
#pragma unroll
    for (int mi = 0; mi < 4; mi++) {
      int row = mi * 16 + lj;
#pragma unroll
      for (int ks = 0; ks < 2; ks++)
        af[mi][ks] = *(const short8*)(aB + row * 128 + ((ks * 64 + hi * 16) ^ ((row & 7) << 4)));
    }
#pragma unroll
    for (int ni = 0; ni < 2; ni++) {
      int row = wave * 32 + ni * 16 + lj;
#pragma unroll
      for (int ks = 0; ks < 2; ks++)
        bfr[ni][ks] = *(const short8*)(bB + row * 128 + ((ks * 64 + hi * 16) ^ ((row & 7) << 4)));
    }
    __builtin_amdgcn_s_setprio(1);
#pragma unroll
    for (int mi = 0; mi < 4; mi++)
#pragma unroll
      for (int ni = 0; ni < 2; ni++)
#pragma unroll
        for (int ks = 0; ks < 2; ks++)
          acc[mi][ni] = __builtin_amdgcn_mfma_f32_16x16x32_bf16(af[mi][ks], bfr[ni][ks],
                                                                acc[mi][ni], 0, 0, 0);
    __builtin_amdgcn_s_setprio(0);
    __builtin_amdgcn_s_barrier();
    cur ^= 1;
  }

  // ---- epilogue: bias + residual, cross-wave LN reduce (16 partials), dual store ----
  float bv[2], gv[2], btv[2];
  int col[2];
#pragma unroll
  for (int ni = 0; ni < 2; ni++) {
    col[ni] = wave * 32 + ni * 16 + lj;
    bv[ni] = bias[col[ni]];
    gv[ni] = gamma[col[ni]];
    btv[ni] = beta[col[ni]];
  }

  float* red = (float*)smem;   // [64 rows][16 waves][2] = 8 KiB (post-loop reuse)

#pragma unroll
  for (int mi = 0; mi < 4; mi++)
#pragma unroll
    for (int r = 0; r < 4; r++) {
      int lrow = mi * 16 + hi * 4 + r;
      size_t rb = (size_t)(m0 + lrow) * 512;
      float s = 0.f, q = 0.f;
#pragma unroll
      for (int ni = 0; ni < 2; ni++) {
        float v = acc[mi][ni][r] + bv[ni] + resid[rb + col[ni]];
        acc[mi][ni][r] = v;
        s += v; q += v * v;
      }
#pragma unroll
      for (int m = 1; m <= 8; m <<= 1) { s += __shfl_xor(s, m); q += __shfl_xor(q, m); }
      if (lj == 0) { red[lrow * 32 + wave * 2] = s; red[lrow * 32 + wave * 2 + 1] = q; }
    }
  __syncthreads();

#pragma unroll
  for (int mi = 0; mi < 4; mi++)
#pragma unroll
    for (int r = 0; r < 4; r++) {
      int lrow = mi * 16 + hi * 4 + r;
      size_t rb = (size_t)(m0 + lrow) * 512;
      float s = 0.f, q = 0.f;
#pragma unroll
      for (int w = 0; w < 16; w++) { s += red[lrow * 32 + w * 2]; q += red[lrow * 32 + w * 2 + 1]; }
      float mu = s * (1.f / 512.f);
      float var = q * (1.f / 512.f) - mu * mu;
      float rs = rsqrtf(fmaxf(var, 0.f) + 1e-5f);
#pragma unroll
      for (int ni = 0; ni < 2; ni++) {
        float y = (acc[mi][ni][r] - mu) * rs * gv[ni] + btv[ni];
        if (STOREF) outF[rb + col[ni]] = y;
        outB[rb + col[ni]] = f2bf(y);
      }
    }
}

// ---------------- AKT attention, one (b, h) per block, 8 waves, balanced --------------
template<bool INCL, bool ZP>
__global__ __launch_bounds__(512) void attn_kernel(
    const u16* __restrict__ qb, const u16* __restrict__ kb, const u16* __restrict__ vb,
    u16* __restrict__ ob, const float* __restrict__ gammas, int li)
{
  __shared__ u16 smem[32768];
  const int tid = threadIdx.x, wave = tid >> 6, lane = tid & 63;
  const int h = blockIdx.x, b = blockIdx.y;
  const int lj = lane & 15, hi = lane >> 4;
  const size_t rowbase = (size_t)b * 256 * 512 + h * 64;

#pragma unroll
  for (int p = 0; p < 2; p++) {
    int r2 = p * 128 + (tid >> 3) * 2;
    int cc = (tid & 7) * 8;
    union { uint4 v; u16 e[8]; } v0, v1;
    uint4 k0 = *(const uint4*)(kb + rowbase + (size_t)r2 * 512 + cc);
    uint4 k1 = *(const uint4*)(kb + rowbase + (size_t)(r2 + 1) * 512 + cc);
    v0.v = *(const uint4*)(vb + rowbase + (size_t)r2 * 512 + cc);
    v1.v = *(const uint4*)(vb + rowbase + (size_t)(r2 + 1) * 512 + cc);
    *(uint4*)((char*)smem + r2 * 128 + ((cc * 2) ^ ((r2 & 7) << 4))) = k0;
    *(uint4*)((char*)smem + (r2 + 1) * 128 + ((cc * 2) ^ (((r2 + 1) & 7) << 4))) = k1;
#pragma unroll
    for (int i = 0; i < 8; i++) {
      int d = cc + i;
      u32 pk = (u32)v0.e[i] | ((u32)v1.e[i] << 16);
      *(u32*)((char*)smem + 32768 + d * 512 + ((2 * r2) ^ ((d & 7) << 4))) = pk;
    }
  }

  const int qt0 = wave, qt1 = 15 - wave;

  short8 qfa[2][2];
#pragma unroll
  for (int cf = 0; cf < 2; cf++) {
    int t = cf ? qt1 : qt0;
#pragma unroll
    for (int s = 0; s < 2; s++)
      qfa[cf][s] = *(const short8*)(qb + rowbase + (size_t)(t * 16 + lj) * 512 + s * 32 + hi * 8);
  }

  float gm = gammas[li * 8 + h];
  float geff = -(gm > 20.f ? gm : log1pf(__expf(gm)));

  __syncthreads();

  const f32x4 zz = {0.f, 0.f, 0.f, 0.f};
  const int hsel = hi >> 1;
  const int sbase = lj + 32 * (hi & 1);

#pragma unroll
  for (int cf = 0; cf < 2; cf++) {
    const int t = cf ? qt1 : qt0;
    const int qb0 = t * 16;
    const int q = qb0 + lj;
    const int nrf = t + 1;
    const int nsp = (t + 2) >> 1;

    f32x4 acc[16], E[16];
#pragma unroll
    for (int rf = 0; rf < 16; rf++) acc[rf] = zz;

#pragma unroll
    for (int rf = 0; rf < 16; rf++) {
      if (rf >= nrf) continue;
      int row = rf * 16 + lj;
#pragma unroll
      for (int s = 0; s < 2; s++) {
        short8 kf = *(const short8*)((char*)smem + row * 128 + ((s * 64 + hi * 16) ^ ((row & 7) << 4)));
        acc[rf] = __builtin_amdgcn_mfma_f32_16x16x32_bf16(kf, qfa[cf][s], acc[rf], 0, 0, 0);
      }
    }

    float mx = -1e30f;
#pragma unroll
    for (int rf = 0; rf < 16; rf++) {
      if (rf >= nrf) continue;
#pragma unroll
      for (int r = 0; r < 4; r++) {
        acc[rf][r] *= 0.125f;
        int k = rf * 16 + hi * 4 + r;
        bool valid = INCL ? (k <= q) : (k < q);
        mx = fmaxf(mx, valid ? acc[rf][r] : -1e30f);
      }
    }
    mx = fmaxf(mx, __shfl_xor(mx, 16));
    mx = fmaxf(mx, __shfl_xor(mx, 32));
    float sum = 0.f;
#pragma unroll
    for (int rf = 0; rf < 16; rf++) {
      if (rf >= nrf) continue;
#pragma unroll
      for (int r = 0; r < 4; r++) {
        int k = rf * 16 + hi * 4 + r;
        bool valid = INCL ? (k <= q) : (k < q);
        float ev = valid ? __expf(acc[rf][r] - mx) : 0.f;
        E[rf][r] = ev;
        sum += ev;
      }
    }
    sum += __shfl_xor(sum, 16);
    sum += __shfl_xor(sum, 32);
    float inv1 = sum > 0.f ? 1.f / sum : 0.f;
    float dtot = sum > 0.f ? 1.f : 0.f;

    float run = 0.f;
#pragma unroll
    for (int rf = 0; rf < 16; rf++) {
      if (rf >= nrf) continue;
      float p[4];
      float pa = 0.f;
#pragma unroll
      for (int r = 0; r < 4; r++) {
        pa += E[rf][r] * inv1;
        p[r] = pa;
      }
      float tl = p[3];
      float v = tl;
      float u1 = __shfl_up(v, 16); v += (hi >= 1) ? u1 : 0.f;
      float u2 = __shfl_up(v, 32); v += (hi >= 2) ? u2 : 0.f;
      float T = __shfl(v, lj + 48);
      float cbase = run + (v - tl);
#pragma unroll
      for (int r = 0; r < 4; r++) {
        int k = rf * 16 + hi * 4 + r;
        bool valid = INCL ? (k <= q) : (k < q);
        float tail = fmaxf(dtot - (cbase + p[r]), 0.f);
        float pos = (float)(q - k);
        float dist = sqrtf(tail * pos);
        float te = fmaxf(__expf(dist * geff), 1e-5f);
        acc[rf][r] = valid ? acc[rf][r] * te : -1e32f;
      }
      run += T;
    }

    float mx2 = -3.0e38f;
#pragma unroll
    for (int rf = 0; rf < 16; rf++) {
      if (rf >= nrf) continue;
#pragma unroll
      for (int r = 0; r < 4; r++) mx2 = fmaxf(mx2, acc[rf][r]);
    }
    mx2 = fmaxf(mx2, __shfl_xor(mx2, 16));
    mx2 = fmaxf(mx2, __shfl_xor(mx2, 32));
    float sum2 = 0.f;
#pragma unroll
    for (int rf = 0; rf < 16; rf++) {
      if (rf >= nrf) continue;
#pragma unroll
      for (int r = 0; r < 4; r++) {
        float ev = __expf(acc[rf][r] - mx2);
        acc[rf][r] = ev;
        sum2 += ev;
      }
    }
    sum2 += __shfl_xor(sum2, 16);
    sum2 += __shfl_xor(sum2, 32);
    float inv = 1.f / sum2;
    if (ZP) { if (q == 0) inv = 0.f; }
#pragma unroll
    for (int rf = 0; rf < 16; rf++) {
      if (rf >= nrf) continue;
#pragma unroll
      for (int r = 0; r < 4; r++) acc[rf][r] *= inv;
    }

    f32x4 oacc[4];
#pragma unroll
    for (int j = 0; j < 4; j++) oacc[j] = zz;

#pragma unroll
    for (int sp = 0; sp < 8; sp++) {
      if (sp >= nsp) continue;
      u32 a0 = cvtpk(acc[2 * sp][0],     acc[2 * sp][1]);
      u32 a1 = cvtpk(acc[2 * sp][2],     acc[2 * sp][3]);
      u32 b0 = cvtpk(acc[2 * sp + 1][0], acc[2 * sp + 1][1]);
      u32 b1 = cvtpk(acc[2 * sp + 1][2], acc[2 * sp + 1][3]);
      u32 pw[4];
#pragma unroll
      for (int tt = 0; tt < 4; tt++) {
        int src = sbase + 16 * (tt >> 1);
        u32 za = (u32)__shfl((int)((tt & 1) ? a1 : a0), src);
        u32 zb = (u32)__shfl((int)((tt & 1) ? b1 : b0), src);
        pw[tt] = hsel ? zb : za;
      }
      short8 pf = __builtin_bit_cast(short8, *(uint4*)pw);
#pragma unroll
      for (int nf = 0; nf < 4; nf++) {
        int d = nf * 16 + lj;
        short8 vf = *(const short8*)((char*)smem + 32768 + d * 512 + ((sp * 64 + hi * 16) ^ ((d & 7) << 4)));
        oacc[nf] = __builtin_amdgcn_mfma_f32_16x16x32_bf16(pf, vf, oacc[nf], 0, 0, 0);
      }
    }

#pragma unroll
    for (int r = 0; r < 4; r++) {
      int qr = qb0 + hi * 4 + r;
      size_t obase = (size_t)(b * 256 + qr) * 512 + h * 64;
#pragma unroll
      for (int nf = 0; nf < 4; nf++)
        ob[obase + nf * 16 + lj] = f2bf(oacc[nf][r]);
    }
  }
}

// ---------------- fp32 -> bf16 convert ------------------------------------------------
__global__ void cvt_kernel(const float* __restrict__ in, u16* __restrict__ out, int n8)
{
  int i = blockIdx.x * 256 + threadIdx.x;
  if (i >= n8) return;
  float4 a = ((const float4*)in)[2 * i], c = ((const float4*)in)[2 * i + 1];
  union { uint4 v; u16 e[8]; } pk;
  pk.e[0]=f2bf(a.x); pk.e[1]=f2bf(a.y); pk.e[2]=f2bf(a.z); pk.e[3]=f2bf(a.w);
  pk.e[4]=f2bf(c.x); pk.e[5]=f2bf(c.y); pk.e[6]=f2bf(c.z); pk.e[7]=f2bf(c.w);
  ((uint4*)out)[i] = pk.v;
}

// ---------------- fp32 [R][C] -> bf16 [C][R] transpose (z-sliced, strided) ------------
__global__ void trans_kernel(const float* __restrict__ in, u16* __restrict__ out,
                             int R, int C, size_t istr, size_t ostr)
{
  __shared__ float tile[32][33];
  in += (size_t)blockIdx.z * istr;
  out += (size_t)blockIdx.z * ostr;
  int c0 = blockIdx.x * 32, r0 = blockIdx.y * 32;
  int tx = threadIdx.x & 31, ty = threadIdx.x >> 5;
#pragma unroll
  for (int i = 0; i < 4; i++) tile[ty + i * 8][tx] = in[(size_t)(r0 + ty + i * 8) * C + c0 + tx];
  __syncthreads();
#pragma unroll
  for (int i = 0; i < 4; i++) out[(size_t)(c0 + ty + i * 8) * R + r0 + tx] = f2bf(tile[tx][ty + i * 8]);
}

// ---------------- bias concat for fused QKV ------------------------------------------
__global__ void bias_concat_kernel(const float* __restrict__ bq, const float* __restrict__ bk,
                                   const float* __restrict__ bv, float* __restrict__ out)
{
  int t = blockIdx.x * 256 + threadIdx.x;
  if (t >= 6 * 1536) return;
  int li = t / 1536, c = t % 1536;
  float v = (c < 512) ? bq[li * 512 + c]
          : (c < 1024) ? bk[li * 512 + c - 512]
                       : bv[li * 512 + c - 1024];
  out[t] = v;
}

// ---------------- final: preds = sigmoid(h2 @ O3 + b) ---------------------------------
__global__ __launch_bounds__(256) void pred_kernel(const u16* __restrict__ h2,
    const float* __restrict__ O3, const float* __restrict__ bO3, float* __restrict__ out)
{
  int row = blockIdx.x * 4 + (threadIdx.x >> 6), lane = threadIdx.x & 63;
  union { uint2 v; u16 e[4]; } hv;
  hv.v = *(const uint2*)(h2 + (size_t)row * 256 + lane * 4);
  float d = 0.f;
#pragma unroll
  for (int i = 0; i < 4; i++) d += bf2f(hv.e[i]) * O3[lane * 4 + i];
#pragma unroll
  for (int m = 1; m <= 32; m <<= 1) d += __shfl_xor(d, m);
  if (lane == 0) out[row] = 1.f / (1.f + expf(-(d + bO3[0])));
}

// ======================================================================================
extern "C" void kernel_launch(void* const* d_in, const int* in_sizes, int n_in,
                              void* d_out, int out_size, void* d_ws, size_t ws_size,
                              hipStream_t stream)
{
  const float* qe   = (const float*)d_in[0];
  const float* qa   = (const float*)d_in[1];
  const float* Wq   = (const float*)d_in[2];  const float* bq  = (const float*)d_in[3];
  const float* Wk   = (const float*)d_in[4];  const float* bk  = (const float*)d_in[5];
  const float* Wv   = (const float*)d_in[6];  const float* bv  = (const float*)d_in[7];
  const float* Wo   = (const float*)d_in[8];  const float* bo  = (const float*)d_in[9];
  const float* gam  = (const float*)d_in[10];
  const float* ln1g = (const float*)d_in[11]; const float* ln1b = (const float*)d_in[12];
  const float* W1   = (const float*)d_in[13]; const float* b1  = (const float*)d_in[14];
  const float* W2   = (const float*)d_in[15]; const float* b2  = (const float*)d_in[16];
  const float* ln2g = (const float*)d_in[17]; const float* ln2b = (const float*)d_in[18];
  const float* O1   = (const float*)d_in[19]; const float* bO1 = (const float*)d_in[20];
  const float* O2   = (const float*)d_in[21]; const float* bO2 = (const float*)d_in[22];
  const float* O3   = (const float*)d_in[23]; const float* bO3 = (const float*)d_in[24];
  float* preds = (float*)d_out;

  const int M = 16384;
  const int BIG = 0x3fffffff;
  char* ws = (char*)d_ws;
  size_t off = 0;
  auto alloc = [&](size_t bytes) { char* p = ws + off; off += (bytes + 255) & ~(size_t)255; return p; };

  u16* wqkvt = (u16*)alloc((size_t)6*1536*512*2);
  u16* wot   = (u16*)alloc((size_t)6*512*512*2);
  u16* w1t   = (u16*)alloc((size_t)6*2048*512*2);
  u16* w2t   = (u16*)alloc((size_t)6*512*2048*2);
  u16* o1t   = (u16*)alloc((size_t)512*1024*2);
  u16* o2t   = (u16*)alloc((size_t)256*512*2);
  float* bqkv = (float*)alloc((size_t)6*1536*4);
  u16* qx  = (u16*)alloc((size_t)M*512*2);
  u16* sA  = (u16*)alloc((size_t)M*512*2);
  u16* sB  = (u16*)alloc((size_t)M*512*2);
  float* g1 = (float*)alloc((size_t)M*512*4);
  u16* region = (u16*)alloc((size_t)M*2048*2);
  u16* qbf = region;
  u16* kbf = region + (size_t)M*512;
  u16* vbf = region + (size_t)2*M*512;
  u16* obf = region + (size_t)3*M*512;
  u16* h1  = region;
  u16* hd1 = region;
  u16* hd2 = region + (size_t)2*M*512;
  (void)ws_size; (void)in_sizes; (void)n_in; (void)out_size;

  trans_kernel<<<dim3(16, 16, 6), 256, 0, stream>>>(Wq, wqkvt,                          512, 512,  (size_t)512*512,  (size_t)1536*512);
  trans_kernel<<<dim3(16, 16, 6), 256, 0, stream>>>(Wk, wqkvt + (size_t)512*512,        512, 512,  (size_t)512*512,  (size_t)1536*512);
  trans_kernel<<<dim3(16, 16, 6), 256, 0, stream>>>(Wv, wqkvt + (size_t)1024*512,       512, 512,  (size_t)512*512,  (size_t)1536*512);
  trans_kernel<<<dim3(16, 16, 6), 256, 0, stream>>>(Wo, wot,                            512, 512,  (size_t)512*512,  (size_t)512*512);
  trans_kernel<<<dim3(64, 16, 6), 256, 0, stream>>>(W1, w1t,                            512, 2048, (size_t)512*2048, (size_t)2048*512);
  trans_kernel<<<dim3(16, 64, 6), 256, 0, stream>>>(W2, w2t,                            2048, 512, (size_t)2048*512, (size_t)512*2048);
  trans_kernel<<<dim3(16, 32, 1), 256, 0, stream>>>(O1, o1t,                            1024, 512, 0, 0);
  trans_kernel<<<dim3(8, 16, 1),  256, 0, stream>>>(O2, o2t,                            512, 256,  0, 0);
  bias_concat_kernel<<<36, 256, 0, stream>>>(bq, bk, bv, bqkv);
  cvt_kernel<<<4096, 256, 0, stream>>>(qe, qx, M * 512 / 8);
  cvt_kernel<<<4096, 256, 0, stream>>>(qa, sA, M * 512 / 8);

  const u16* curB = sA;
  const float* curF = qa;
  const u16* yfin = nullptr;
  const dim3 gA(8, 64);

  for (int li = 0; li < 6; li++) {
    bool ffn  = (li == 0 || li == 1 || li == 3 || li == 5);
    bool excl = (li == 3 || li == 5);
    size_t wqkv_off = (size_t)li * 1536 * 512;

    // fused QKV (non-excl: all three from curB; excl: Q,K from curB, V from yfin)
    gemm256_kernel<false, true><<<dim3(64, 6), 512, 0, stream>>>(
        curB, excl ? yfin : curB, 512, wqkvt + wqkv_off, 512, bqkv + li * 1536,
        qbf, kbf, vbf, 512);

    if (!excl) attn_kernel<true,  false><<<gA, 512, 0, stream>>>(qbf, kbf, vbf, obf, gam, li);
    else       attn_kernel<false, true ><<<gA, 512, 0, stream>>>(qbf, kbf, vbf, obf, gam, li);

    // fused Wo-proj + residual + LN1 -> (g1 fp32, sB bf16)
    gemmln_kernel<true><<<256, 1024, 0, stream>>>(
        obf, 512, wot + (size_t)li * 512 * 512, 512, bo + li * 512,
        curF, ln1g + li * 512, ln1b + li * 512, g1, sB);
    curB = sB; curF = g1;

    if (ffn) {
      gemm256_kernel<true, false><<<dim3(64, 8), 512, 0, stream>>>(
          curB, nullptr, 512, w1t + (size_t)li * 2048 * 512, 512, b1 + li * 2048,
          h1, nullptr, nullptr, 2048);
      u16* nB = (li < 2) ? sA : sB;
      // fused W2-proj + residual + LN2; fp32 out dead after li=1 / li=5 -> skip store
      if (li == 1 || li == 5)
        gemmln_kernel<false><<<256, 1024, 0, stream>>>(
            h1, 2048, w2t + (size_t)li * 512 * 2048, 2048, b2 + li * 512,
            g1, ln2g + li * 512, ln2b + li * 512, g1, nB);
      else
        gemmln_kernel<true><<<256, 1024, 0, stream>>>(
            h1, 2048, w2t + (size_t)li * 512 * 2048, 2048, b2 + li * 512,
            g1, ln2g + li * 512, ln2b + li * 512, g1, nB);
      curB = nB;
    }
    if (li == 1) { yfin = curB; curB = qx; curF = qe; }
  }

  gemm_kernel<true, true, false, false><<<dim3(128, 4), 256, 0, stream>>>(
      curB, qx, 512, 512, 512, o1t, 1024, bO1, nullptr, nullptr, hd1, nullptr, nullptr, 512);
  gemm_kernel<true, true, false, false><<<dim3(128, 2), 256, 0, stream>>>(
      hd1, hd1, BIG, 512, 512, o2t, 512, bO2, nullptr, nullptr, hd2, nullptr, nullptr, 256);
  pred_kernel<<<4096, 256, 0, stream>>>(hd2, O3, bO3, preds);
}

// Round 18
// 1208.617 us; speedup vs baseline: 1.0874x; 1.0874x over previous
//
#include <hip/hip_runtime.h>

typedef unsigned short u16;
typedef unsigned int u32;
typedef short short8 __attribute__((ext_vector_type(8)));
typedef float f32x4 __attribute__((ext_vector_type(4)));

#define DEV static __device__ __forceinline__

DEV u16 f2bf(float f) {
  u32 u = __builtin_bit_cast(u32, f);
  u32 r = u + 0x7FFFu + ((u >> 16) & 1u);
  return (u16)(r >> 16);
}
DEV float bf2f(u16 h) { u32 u = ((u32)h) << 16; return __builtin_bit_cast(float, u); }

DEV u32 cvtpk(float lo, float hi_) {
  u32 r;
  asm("v_cvt_pk_bf16_f32 %0, %1, %2" : "=v"(r) : "v"(lo), "v"(hi_));
  return r;
}

DEV void async16(const u16* g, u16* l) {
  __builtin_amdgcn_global_load_lds((const __attribute__((address_space(1))) void*)g,
                                   (__attribute__((address_space(3))) void*)l, 16, 0, 0);
}

// ---------------- 128-tile bf16 MFMA GEMM (2-phase) — head GEMMs ---------------------
template<bool RELU, bool OUTBF, bool RESID, bool SPLIT3>
__global__ __launch_bounds__(256, 2) void gemm_kernel(
    const u16* __restrict__ A, const u16* __restrict__ A2, int KA,
    int lda, int lda2,
    const u16* __restrict__ Bt, int K,
    const float* __restrict__ bias, const float* __restrict__ resid,
    float* __restrict__ Cf, u16* __restrict__ Cb, u16* __restrict__ Cb2, u16* __restrict__ Cb3,
    int ldc)
{
  __shared__ u16 smem[2][16384];   // [buf][A 8192 | B 8192] = 64 KiB
  const int tid = threadIdx.x, wave = tid >> 6, lane = tid & 63;
  const int m0 = blockIdx.x * 128, n0 = blockIdx.y * 128;
  const int wr = wave >> 1, wc = wave & 1;
  const int lj = lane & 15, hi = lane >> 4;

  f32x4 acc[4][4];
  const f32x4 zz = {0.f, 0.f, 0.f, 0.f};
#pragma unroll
  for (int i = 0; i < 4; i++)
#pragma unroll
    for (int j = 0; j < 4; j++) acc[i][j] = zz;

  const int nkt = K / 64;

  auto stage = [&](int buf, int kt) {
    int kofs = kt * 64;
    const u16* sa; int la;
    if (kofs < KA) { sa = A + kofs; la = lda; }
    else           { sa = A2 + (kofs - KA); la = lda2; }
#pragma unroll
    for (int i = 0; i < 8; i++) {
      int c = wave * 8 + i;
      if (c < 16) {
        const u16* g = sa + (size_t)(m0 + c * 8 + (lane >> 3)) * la + (lane & 7) * 8;
        async16(g, &smem[buf][c * 512]);
      } else {
        const u16* g = Bt + (size_t)(n0 + (c - 16) * 8 + (lane >> 3)) * K + kofs + (lane & 7) * 8;
        async16(g, &smem[buf][c * 512]);
      }
    }
  };

  stage(0, 0);
  int cur = 0;
  for (int kt = 0; kt < nkt; kt++) {
    __syncthreads();
    if (kt + 1 < nkt) stage(cur ^ 1, kt + 1);
    const u16* la_ = &smem[cur][0];
    const u16* lb_ = &smem[cur][8192];
#pragma unroll
    for (int ks = 0; ks < 2; ks++) {
      short8 af[4], bfr[4];
#pragma unroll
      for (int mi = 0; mi < 4; mi++)
        af[mi] = *(const short8*)(la_ + (wr * 64 + mi * 16 + lj) * 64 + ks * 32 + hi * 8);
#pragma unroll
      for (int ni = 0; ni < 4; ni++)
        bfr[ni] = *(const short8*)(lb_ + (wc * 64 + ni * 16 + lj) * 64 + ks * 32 + hi * 8);
#pragma unroll
      for (int mi = 0; mi < 4; mi++)
#pragma unroll
        for (int ni = 0; ni < 4; ni++)
          acc[mi][ni] = __builtin_amdgcn_mfma_f32_16x16x32_bf16(af[mi], bfr[ni], acc[mi][ni], 0, 0, 0);
    }
    cur ^= 1;
  }

  u16* outB = Cb;
  int nloc = n0;
  if (SPLIT3) {
    int sec = n0 >> 9;
    outB = (sec == 0) ? Cb : (sec == 1) ? Cb2 : Cb3;
    nloc = n0 & 511;
  }

  float bv[4];
#pragma unroll
  for (int ni = 0; ni < 4; ni++) bv[ni] = bias[n0 + wc * 64 + ni * 16 + lj];
#pragma unroll
  for (int mi = 0; mi < 4; mi++)
#pragma unroll
    for (int r = 0; r < 4; r++) {
      int row = m0 + wr * 64 + mi * 16 + hi * 4 + r;
      size_t rb = (size_t)row * ldc;
#pragma unroll
      for (int ni = 0; ni < 4; ni++) {
        int col = nloc + wc * 64 + ni * 16 + lj;
        float v = acc[mi][ni][r] + bv[ni];
        if (RESID) v += resid[rb + col];
        if (RELU) v = fmaxf(v, 0.f);
        if (OUTBF) outB[rb + col] = f2bf(v);
        else Cf[rb + col] = v;
      }
    }
}

// ---------------- 256-tile bf16 MFMA GEMM, ONE phase per K-tile — QKV/QK+V/W1 --------
template<bool RELU, bool SPLIT3>
__global__ __launch_bounds__(512) void gemm256_kernel(
    const u16* __restrict__ A, const u16* __restrict__ A2v, int lda,
    const u16* __restrict__ Bt, int K,
    const float* __restrict__ bias,
    u16* __restrict__ Cb, u16* __restrict__ Cb2, u16* __restrict__ Cb3, int ldc)
{
  __shared__ u16 smem[65536];  // A: buf*16384 ; B: 32768 + buf*16384 (elems), 128 KiB
  const int tid = threadIdx.x, wave = tid >> 6, lane = tid & 63;
  const int m0 = blockIdx.x * 256, n0 = blockIdx.y * 256;
  const int wm = wave >> 2, wn = wave & 3;
  const int lj = lane & 15, hi = lane >> 4;
  const int srow = wave * 8 + (lane >> 3);
  const int schunk = (lane & 7) ^ ((lane >> 3) & 7);

  const u16* Asrc = (SPLIT3 && (n0 >> 9) == 2 && A2v) ? A2v : A;

  f32x4 acc[8][4];
  const f32x4 zz = {0.f, 0.f, 0.f, 0.f};
#pragma unroll
  for (int i = 0; i < 8; i++)
#pragma unroll
    for (int j = 0; j < 4; j++) acc[i][j] = zz;

  const int nkt = K / 64;

  auto stageA = [&](int buf, int kt, int seg) {
    const u16* g = Asrc + (size_t)(m0 + seg * 64 + srow) * lda + kt * 64 + schunk * 8;
    async16(g, &smem[buf * 16384 + (seg * 64 + wave * 8) * 64]);
  };
  auto stageB = [&](int buf, int kt, int seg) {
    const u16* g = Bt + (size_t)(n0 + seg * 64 + srow) * K + kt * 64 + schunk * 8;
    async16(g, &smem[32768 + buf * 16384 + (seg * 64 + wave * 8) * 64]);
  };

#pragma unroll
  for (int seg = 0; seg < 4; seg++) stageA(0, 0, seg);
#pragma unroll
  for (int seg = 0; seg < 4; seg++) stageB(0, 0, seg);

  int cur = 0;
  for (int t = 0; t < nkt; t++) {
    const bool pf = (t + 1 < nkt);
    const char* aB = (const char*)smem + cur * 32768;
    const char* bB = (const char*)smem + 65536 + cur * 32768;

    if (pf) {
#pragma unroll
      for (int seg = 0; seg < 4; seg++) stageA(cur ^ 1, t + 1, seg);
#pragma unroll
      for (int seg = 0; seg < 4; seg++) stageB(cur ^ 1, t + 1, seg);
    }
    if (pf) asm volatile("s_waitcnt vmcnt(8)" ::: "memory");
    else    asm volatile("s_waitcnt vmcnt(0)" ::: "memory");
    __builtin_amdgcn_s_barrier();

    short8 bfr[4][2];
#pragma unroll
    for (int ni = 0; ni < 4; ni++) {
      int row = wn * 64 + ni * 16 + lj;
#pragma unroll
      for (int ks = 0; ks < 2; ks++)
        bfr[ni][ks] = *(const short8*)(bB + row * 128 + ((ks * 64 + hi * 16) ^ ((row & 7) << 4)));
    }
#pragma unroll
    for (int mh = 0; mh < 2; mh++) {
      short8 af[4][2];
#pragma unroll
      for (int mi = 0; mi < 4; mi++) {
        int row = wm * 128 + (mh * 4 + mi) * 16 + lj;
#pragma unroll
        for (int ks = 0; ks < 2; ks++)
          af[mi][ks] = *(const short8*)(aB + row * 128 + ((ks * 64 + hi * 16) ^ ((row & 7) << 4)));
      }
      __builtin_amdgcn_s_setprio(1);
#pragma unroll
      for (int mi = 0; mi < 4; mi++)
#pragma unroll
        for (int ni = 0; ni < 4; ni++)
#pragma unroll
          for (int ks = 0; ks < 2; ks++)
            acc[mh * 4 + mi][ni] =
                __builtin_amdgcn_mfma_f32_16x16x32_bf16(af[mi][ks], bfr[ni][ks],
                                                        acc[mh * 4 + mi][ni], 0, 0, 0);
      __builtin_amdgcn_s_setprio(0);
    }
    __builtin_amdgcn_s_barrier();
    cur ^= 1;
  }

  u16* outB = Cb;
  int nloc = n0;
  if (SPLIT3) {
    int sec = n0 >> 9;
    outB = (sec == 0) ? Cb : (sec == 1) ? Cb2 : Cb3;
    nloc = n0 & 511;
  }

  float bv[4];
#pragma unroll
  for (int ni = 0; ni < 4; ni++) bv[ni] = bias[n0 + wn * 64 + ni * 16 + lj];
#pragma unroll
  for (int mi = 0; mi < 8; mi++)
#pragma unroll
    for (int r = 0; r < 4; r++) {
      int row = m0 + wm * 128 + mi * 16 + hi * 4 + r;
      size_t rb = (size_t)row * ldc;
#pragma unroll
      for (int ni = 0; ni < 4; ni++) {
        int col = nloc + wn * 64 + ni * 16 + lj;
        float v = acc[mi][ni][r] + bv[ni];
        if (RELU) v = fmaxf(v, 0.f);
        outB[rb + col] = f2bf(v);
      }
    }
}

// ---------------- fused GEMM + bias + residual + LayerNorm (N=512 full-row tile) -----
// r13 structure (empirical best across 6 ablations): A+B via global_load_lds, 144 KiB
// dbuf LDS, ONE phase per K-tile {issue 9 next-tile loads ; vmcnt(9) ; barrier ;
// 16 ds_read ; setprio(1) 32 MFMA setprio(0) ; barrier}. STOREF=false skips the
// fp32 output (dead for li=1/li=5 LN2).
template<bool STOREF>
__global__ __launch_bounds__(512) void gemmln_kernel(
    const u16* __restrict__ A, int lda,
    const u16* __restrict__ Bt, int K,
    const float* __restrict__ bias, const float* __restrict__ resid,
    const float* __restrict__ gamma, const float* __restrict__ beta,
    float* __restrict__ outF, u16* __restrict__ outB)
{
  __shared__ u16 smem[73728];  // A: buf*8192 B ; B: 16384 + buf*65536 B (144 KiB)
  const int tid = threadIdx.x, wave = tid >> 6, lane = tid & 63;
  const int m0 = blockIdx.x * 64;
  const int lj = lane & 15, hi = lane >> 4;
  const int srow = lane >> 3;
  const int schunk = (lane & 7) ^ ((lane >> 3) & 7);

  f32x4 acc[4][4];
  const f32x4 zz = {0.f, 0.f, 0.f, 0.f};
#pragma unroll
  for (int i = 0; i < 4; i++)
#pragma unroll
    for (int j = 0; j < 4; j++) acc[i][j] = zz;

  const int nkt = K / 64;

  auto stageA = [&](int buf, int kt) {
    const u16* g = A + (size_t)(m0 + wave * 8 + srow) * lda + kt * 64 + schunk * 8;
    async16(g, &smem[buf * 4096 + (wave * 8) * 64]);
  };
  auto stageB = [&](int buf, int kt, int seg) {
    const u16* g = Bt + (size_t)(seg * 64 + wave * 8 + srow) * K + kt * 64 + schunk * 8;
    async16(g, &smem[8192 + buf * 32768 + (seg * 64 + wave * 8) * 64]);
  };

  stageA(0, 0);
#pragma unroll
  for (int seg = 0; seg < 8; seg++) stageB(0, 0, seg);

  int cur = 0;
  for (int t = 0; t < nkt; t++) {
    const bool pf = (t + 1 < nkt);
    if (pf) {
      stageA(cur ^ 1, t + 1);
#pragma unroll
      for (int seg = 0; seg < 8; seg++) stageB(cur ^ 1, t + 1, seg);
    }
    if (pf) asm volatile("s_waitcnt vmcnt(9)" ::: "memory");
    else    asm volatile("s_waitcnt vmcnt(0)" ::: "memory");
    __builtin_amdgcn_s_barrier();

    const char* aB = (const char*)smem + cur * 8192;
    const char* bB = (const char*)smem + 16384 + cur * 65536;
    short8 af[4][2], bfr[4][2];
#pragma unroll
    for (int mi = 0; mi < 4; mi++) {
      int row = mi * 16 + lj;
#pragma unroll
      for (int ks = 0; ks < 2; ks++)
        af[mi][ks] = *(const short8*)(aB + row * 128 + ((ks * 64 + hi * 16) ^ ((row & 7) << 4)));
    }
#pragma unroll
    for (int ni = 0; ni < 4; ni++) {
      int row = wave * 64 + ni * 16 + lj;
#pragma unroll
      for (int ks = 0; ks < 2; ks++)
        bfr[ni][ks] = *(const short8*)(bB + row * 128 + ((ks * 64 + hi * 16) ^ ((row & 7) << 4)));
    }
    __builtin_amdgcn_s_setprio(1);
#pragma unroll
    for (int mi = 0; mi < 4; mi++)
#pragma unroll
      for (int ni = 0; ni < 4; ni++)
#pragma unroll
        for (int ks = 0; ks < 2; ks++)
          acc[mi][ni] = __builtin_amdgcn_mfma_f32_16x16x32_bf16(af[mi][ks], bfr[ni][ks],
                                                                acc[mi][ni], 0, 0, 0);
    __builtin_amdgcn_s_setprio(0);
    __builtin_amdgcn_s_barrier();
    cur ^= 1;
  }

  // ---- epilogue: bias + residual, cross-wave LN reduce, scale, dual store ----
  float bv[4], gv[4], btv[4];
  int col[4];
#pragma unroll
  for (int ni = 0; ni < 4; ni++) {
    col[ni] = wave * 64 + ni * 16 + lj;
    bv[ni] = bias[col[ni]];
    gv[ni] = gamma[col[ni]];
    btv[ni] = beta[col[ni]];
  }

  float* red = (float*)smem;   // [64 rows][8 waves][2] = 4 KiB (post-loop reuse)

#pragma unroll
  for (int mi = 0; mi < 4; mi++)
#pragma unroll
    for (int r = 0; r < 4; r++) {
      int lrow = mi * 16 + hi * 4 + r;
      size_t rb = (size_t)(m0 + lrow) * 512;
      float s = 0.f, q = 0.f;
#pragma unroll
      for (int ni = 0; ni < 4; ni++) {
        float v = acc[mi][ni][r] + bv[ni] + resid[rb + col[ni]];
        acc[mi][ni][r] = v;
        s += v; q += v * v;
      }
#pragma unroll
      for (int m = 1; m <= 8; m <<= 1) { s += __shfl_xor(s, m); q += __shfl_xor(q, m); }
      if (lj == 0) { red[lrow * 16 + wave * 2] = s; red[lrow * 16 + wave * 2 + 1] = q; }
    }
  __syncthreads();

#pragma unroll
  for (int mi = 0; mi < 4; mi++)
#pragma unroll
    for (int r = 0; r < 4; r++) {
      int lrow = mi * 16 + hi * 4 + r;
      size_t rb = (size_t)(m0 + lrow) * 512;
      float s = 0.f, q = 0.f;
#pragma unroll
      for (int w = 0; w < 8; w++) { s += red[lrow * 16 + w * 2]; q += red[lrow * 16 + w * 2 + 1]; }
      float mu = s * (1.f / 512.f);
      float var = q * (1.f / 512.f) - mu * mu;
      float rs = rsqrtf(fmaxf(var, 0.f) + 1e-5f);
#pragma unroll
      for (int ni = 0; ni < 4; ni++) {
        float y = (acc[mi][ni][r] - mu) * rs * gv[ni] + btv[ni];
        if (STOREF) outF[rb + col[ni]] = y;
        outB[rb + col[ni]] = f2bf(y);
      }
    }
}

// ---------------- AKT attention, one (b, h) per block, 8 waves, balanced --------------
template<bool INCL, bool ZP>
__global__ __launch_bounds__(512) void attn_kernel(
    const u16* __restrict__ qb, const u16* __restrict__ kb, const u16* __restrict__ vb,
    u16* __restrict__ ob, const float* __restrict__ gammas, int li)
{
  __shared__ u16 smem[32768];
  const int tid = threadIdx.x, wave = tid >> 6, lane = tid & 63;
  const int h = blockIdx.x, b = blockIdx.y;
  const int lj = lane & 15, hi = lane >> 4;
  const size_t rowbase = (size_t)b * 256 * 512 + h * 64;

#pragma unroll
  for (int p = 0; p < 2; p++) {
    int r2 = p * 128 + (tid >> 3) * 2;
    int cc = (tid & 7) * 8;
    union { uint4 v; u16 e[8]; } v0, v1;
    uint4 k0 = *(const uint4*)(kb + rowbase + (size_t)r2 * 512 + cc);
    uint4 k1 = *(const uint4*)(kb + rowbase + (size_t)(r2 + 1) * 512 + cc);
    v0.v = *(const uint4*)(vb + rowbase + (size_t)r2 * 512 + cc);
    v1.v = *(const uint4*)(vb + rowbase + (size_t)(r2 + 1) * 512 + cc);
    *(uint4*)((char*)smem + r2 * 128 + ((cc * 2) ^ ((r2 & 7) << 4))) = k0;
    *(uint4*)((char*)smem + (r2 + 1) * 128 + ((cc * 2) ^ (((r2 + 1) & 7) << 4))) = k1;
#pragma unroll
    for (int i = 0; i < 8; i++) {
      int d = cc + i;
      u32 pk = (u32)v0.e[i] | ((u32)v1.e[i] << 16);
      *(u32*)((char*)smem + 32768 + d * 512 + ((2 * r2) ^ ((d & 7) << 4))) = pk;
    }
  }

  const int qt0 = wave, qt1 = 15 - wave;

  short8 qfa[2][2];
#pragma unroll
  for (int cf = 0; cf < 2; cf++) {
    int t = cf ? qt1 : qt0;
#pragma unroll
    for (int s = 0; s < 2; s++)
      qfa[cf][s] = *(const short8*)(qb + rowbase + (size_t)(t * 16 + lj) * 512 + s * 32 + hi * 8);
  }

  float gm = gammas[li * 8 + h];
  float geff = -(gm > 20.f ? gm : log1pf(__expf(gm)));

  __syncthreads();

  const f32x4 zz = {0.f, 0.f, 0.f, 0.f};
  const int hsel = hi >> 1;
  const int sbase = lj + 32 * (hi & 1);

#pragma unroll
  for (int cf = 0; cf < 2; cf++) {
    const int t = cf ? qt1 : qt0;
    const int qb0 = t * 16;
    const int q = qb0 + lj;
    const int nrf = t + 1;
    const int nsp = (t + 2) >> 1;

    f32x4 acc[16], E[16];
#pragma unroll
    for (int rf = 0; rf < 16; rf++) acc[rf] = zz;

#pragma unroll
    for (int rf = 0; rf < 16; rf++) {
      if (rf >= nrf) continue;
      int row = rf * 16 + lj;
#pragma unroll
      for (int s = 0; s < 2; s++) {
        short8 kf = *(const short8*)((char*)smem + row * 128 + ((s * 64 + hi * 16) ^ ((row & 7) << 4)));
        acc[rf] = __builtin_amdgcn_mfma_f32_16x16x32_bf16(kf, qfa[cf][s], acc[rf], 0, 0, 0);
      }
    }

    float mx = -1e30f;
#pragma unroll
    for (int rf = 0; rf < 16; rf++) {
      if (rf >= nrf) continue;
#pragma unroll
      for (int r = 0; r < 4; r++) {
        acc[rf][r] *= 0.125f;
        int k = rf * 16 + hi * 4 + r;
        bool valid = INCL ? (k <= q) : (k < q);
        mx = fmaxf(mx, valid ? acc[rf][r] : -1e30f);
      }
    }
    mx = fmaxf(mx, __shfl_xor(mx, 16));
    mx = fmaxf(mx, __shfl_xor(mx, 32));
    float sum = 0.f;
#pragma unroll
    for (int rf = 0; rf < 16; rf++) {
      if (rf >= nrf) continue;
#pragma unroll
      for (int r = 0; r < 4; r++) {
        int k = rf * 16 + hi * 4 + r;
        bool valid = INCL ? (k <= q) : (k < q);
        float ev = valid ? __expf(acc[rf][r] - mx) : 0.f;
        E[rf][r] = ev;
        sum += ev;
      }
    }
    sum += __shfl_xor(sum, 16);
    sum += __shfl_xor(sum, 32);
    float inv1 = sum > 0.f ? 1.f / sum : 0.f;
    float dtot = sum > 0.f ? 1.f : 0.f;

    float run = 0.f;
#pragma unroll
    for (int rf = 0; rf < 16; rf++) {
      if (rf >= nrf) continue;
      float p[4];
      float pa = 0.f;
#pragma unroll
      for (int r = 0; r < 4; r++) {
        pa += E[rf][r] * inv1;
        p[r] = pa;
      }
      float tl = p[3];
      float v = tl;
      float u1 = __shfl_up(v, 16); v += (hi >= 1) ? u1 : 0.f;
      float u2 = __shfl_up(v, 32); v += (hi >= 2) ? u2 : 0.f;
      float T = __shfl(v, lj + 48);
      float cbase = run + (v - tl);
#pragma unroll
      for (int r = 0; r < 4; r++) {
        int k = rf * 16 + hi * 4 + r;
        bool valid = INCL ? (k <= q) : (k < q);
        float tail = fmaxf(dtot - (cbase + p[r]), 0.f);
        float pos = (float)(q - k);
        float dist = sqrtf(tail * pos);
        float te = fmaxf(__expf(dist * geff), 1e-5f);
        acc[rf][r] = valid ? acc[rf][r] * te : -1e32f;
      }
      run += T;
    }

    float mx2 = -3.0e38f;
#pragma unroll
    for (int rf = 0; rf < 16; rf++) {
      if (rf >= nrf) continue;
#pragma unroll
      for (int r = 0; r < 4; r++) mx2 = fmaxf(mx2, acc[rf][r]);
    }
    mx2 = fmaxf(mx2, __shfl_xor(mx2, 16));
    mx2 = fmaxf(mx2, __shfl_xor(mx2, 32));
    float sum2 = 0.f;
#pragma unroll
    for (int rf = 0; rf < 16; rf++) {
      if (rf >= nrf) continue;
#pragma unroll
      for (int r = 0; r < 4; r++) {
        float ev = __expf(acc[rf][r] - mx2);
        acc[rf][r] = ev;
        sum2 += ev;
      }
    }
    sum2 += __shfl_xor(sum2, 16);
    sum2 += __shfl_xor(sum2, 32);
    float inv = 1.f / sum2;
    if (ZP) { if (q == 0) inv = 0.f; }
#pragma unroll
    for (int rf = 0; rf < 16; rf++) {
      if (rf >= nrf) continue;
#pragma unroll
      for (int r = 0; r < 4; r++) acc[rf][r] *= inv;
    }

    f32x4 oacc[4];
#pragma unroll
    for (int j = 0; j < 4; j++) oacc[j] = zz;

#pragma unroll
    for (int sp = 0; sp < 8; sp++) {
      if (sp >= nsp) continue;
      u32 a0 = cvtpk(acc[2 * sp][0],     acc[2 * sp][1]);
      u32 a1 = cvtpk(acc[2 * sp][2],     acc[2 * sp][3]);
      u32 b0 = cvtpk(acc[2 * sp + 1][0], acc[2 * sp + 1][1]);
      u32 b1 = cvtpk(acc[2 * sp + 1][2], acc[2 * sp + 1][3]);
      u32 pw[4];
#pragma unroll
      for (int tt = 0; tt < 4; tt++) {
        int src = sbase + 16 * (tt >> 1);
        u32 za = (u32)__shfl((int)((tt & 1) ? a1 : a0), src);
        u32 zb = (u32)__shfl((int)((tt & 1) ? b1 : b0), src);
        pw[tt] = hsel ? zb : za;
      }
      short8 pf = __builtin_bit_cast(short8, *(uint4*)pw);
#pragma unroll
      for (int nf = 0; nf < 4; nf++) {
        int d = nf * 16 + lj;
        short8 vf = *(const short8*)((char*)smem + 32768 + d * 512 + ((sp * 64 + hi * 16) ^ ((d & 7) << 4)));
        oacc[nf] = __builtin_amdgcn_mfma_f32_16x16x32_bf16(pf, vf, oacc[nf], 0, 0, 0);
      }
    }

#pragma unroll
    for (int r = 0; r < 4; r++) {
      int qr = qb0 + hi * 4 + r;
      size_t obase = (size_t)(b * 256 + qr) * 512 + h * 64;
#pragma unroll
      for (int nf = 0; nf < 4; nf++)
        ob[obase + nf * 16 + lj] = f2bf(oacc[nf][r]);
    }
  }
}

// ---------------- fp32 -> bf16 convert ------------------------------------------------
__global__ void cvt_kernel(const float* __restrict__ in, u16* __restrict__ out, int n8)
{
  int i = blockIdx.x * 256 + threadIdx.x;
  if (i >= n8) return;
  float4 a = ((const float4*)in)[2 * i], c = ((const float4*)in)[2 * i + 1];
  union { uint4 v; u16 e[8]; } pk;
  pk.e[0]=f2bf(a.x); pk.e[1]=f2bf(a.y); pk.e[2]=f2bf(a.z); pk.e[3]=f2bf(a.w);
  pk.e[4]=f2bf(c.x); pk.e[5]=f2bf(c.y); pk.e[6]=f2bf(c.z); pk.e[7]=f2bf(c.w);
  ((uint4*)out)[i] = pk.v;
}

// ---------------- fp32 [R][C] -> bf16 [C][R] transpose (z-sliced, strided) ------------
__global__ void trans_kernel(const float* __restrict__ in, u16* __restrict__ out,
                             int R, int C, size_t istr, size_t ostr)
{
  __shared__ float tile[32][33];
  in += (size_t)blockIdx.z * istr;
  out += (size_t)blockIdx.z * ostr;
  int c0 = blockIdx.x * 32, r0 = blockIdx.y * 32;
  int tx = threadIdx.x & 31, ty = threadIdx.x >> 5;
#pragma unroll
  for (int i = 0; i < 4; i++) tile[ty + i * 8][tx] = in[(size_t)(r0 + ty + i * 8) * C + c0 + tx];
  __syncthreads();
#pragma unroll
  for (int i = 0; i < 4; i++) out[(size_t)(c0 + ty + i * 8) * R + r0 + tx] = f2bf(tile[tx][ty + i * 8]);
}

// ---------------- bias concat for fused QKV ------------------------------------------
__global__ void bias_concat_kernel(const float* __restrict__ bq, const float* __restrict__ bk,
                                   const float* __restrict__ bv, float* __restrict__ out)
{
  int t = blockIdx.x * 256 + threadIdx.x;
  if (t >= 6 * 1536) return;
  int li = t / 1536, c = t % 1536;
  float v = (c < 512) ? bq[li * 512 + c]
          : (c < 1024) ? bk[li * 512 + c - 512]
                       : bv[li * 512 + c - 1024];
  out[t] = v;
}

// ---------------- final: preds = sigmoid(h2 @ O3 + b) ---------------------------------
__global__ __launch_bounds__(256) void pred_kernel(const u16* __restrict__ h2,
    const float* __restrict__ O3, const float* __restrict__ bO3, float* __restrict__ out)
{
  int row = blockIdx.x * 4 + (threadIdx.x >> 6), lane = threadIdx.x & 63;
  union { uint2 v; u16 e[4]; } hv;
  hv.v = *(const uint2*)(h2 + (size_t)row * 256 + lane * 4);
  float d = 0.f;
#pragma unroll
  for (int i = 0; i < 4; i++) d += bf2f(hv.e[i]) * O3[lane * 4 + i];
#pragma unroll
  for (int m = 1; m <= 32; m <<= 1) d += __shfl_xor(d, m);
  if (lane == 0) out[row] = 1.f / (1.f + expf(-(d + bO3[0])));
}

// ======================================================================================
extern "C" void kernel_launch(void* const* d_in, const int* in_sizes, int n_in,
                              void* d_out, int out_size, void* d_ws, size_t ws_size,
                              hipStream_t stream)
{
  const float* qe   = (const float*)d_in[0];
  const float* qa   = (const float*)d_in[1];
  const float* Wq   = (const float*)d_in[2];  const float* bq  = (const float*)d_in[3];
  const float* Wk   = (const float*)d_in[4];  const float* bk  = (const float*)d_in[5];
  const float* Wv   = (const float*)d_in[6];  const float* bv  = (const float*)d_in[7];
  const float* Wo   = (const float*)d_in[8];  const float* bo  = (const float*)d_in[9];
  const float* gam  = (const float*)d_in[10];
  const float* ln1g = (const float*)d_in[11]; const float* ln1b = (const float*)d_in[12];
  const float* W1   = (const float*)d_in[13]; const float* b1  = (const float*)d_in[14];
  const float* W2   = (const float*)d_in[15]; const float* b2  = (const float*)d_in[16];
  const float* ln2g = (const float*)d_in[17]; const float* ln2b = (const float*)d_in[18];
  const float* O1   = (const float*)d_in[19]; const float* bO1 = (const float*)d_in[20];
  const float* O2   = (const float*)d_in[21]; const float* bO2 = (const float*)d_in[22];
  const float* O3   = (const float*)d_in[23]; const float* bO3 = (const float*)d_in[24];
  float* preds = (float*)d_out;

  const int M = 16384;
  const int BIG = 0x3fffffff;
  char* ws = (char*)d_ws;
  size_t off = 0;
  auto alloc = [&](size_t bytes) { char* p = ws + off; off += (bytes + 255) & ~(size_t)255; return p; };

  u16* wqkvt = (u16*)alloc((size_t)6*1536*512*2);
  u16* wot   = (u16*)alloc((size_t)6*512*512*2);
  u16* w1t   = (u16*)alloc((size_t)6*2048*512*2);
  u16* w2t   = (u16*)alloc((size_t)6*512*2048*2);
  u16* o1t   = (u16*)alloc((size_t)512*1024*2);
  u16* o2t   = (u16*)alloc((size_t)256*512*2);
  float* bqkv = (float*)alloc((size_t)6*1536*4);
  u16* qx  = (u16*)alloc((size_t)M*512*2);
  u16* sA  = (u16*)alloc((size_t)M*512*2);
  u16* sB  = (u16*)alloc((size_t)M*512*2);
  float* g1 = (float*)alloc((size_t)M*512*4);
  u16* region = (u16*)alloc((size_t)M*2048*2);
  u16* qbf = region;
  u16* kbf = region + (size_t)M*512;
  u16* vbf = region + (size_t)2*M*512;
  u16* obf = region + (size_t)3*M*512;
  u16* h1  = region;
  u16* hd1 = region;
  u16* hd2 = region + (size_t)2*M*512;
  (void)ws_size; (void)in_sizes; (void)n_in; (void)out_size;

  trans_kernel<<<dim3(16, 16, 6), 256, 0, stream>>>(Wq, wqkvt,                          512, 512,  (size_t)512*512,  (size_t)1536*512);
  trans_kernel<<<dim3(16, 16, 6), 256, 0, stream>>>(Wk, wqkvt + (size_t)512*512,        512, 512,  (size_t)512*512,  (size_t)1536*512);
  trans_kernel<<<dim3(16, 16, 6), 256, 0, stream>>>(Wv, wqkvt + (size_t)1024*512,       512, 512,  (size_t)512*512,  (size_t)1536*512);
  trans_kernel<<<dim3(16, 16, 6), 256, 0, stream>>>(Wo, wot,                            512, 512,  (size_t)512*512,  (size_t)512*512);
  trans_kernel<<<dim3(64, 16, 6), 256, 0, stream>>>(W1, w1t,                            512, 2048, (size_t)512*2048, (size_t)2048*512);
  trans_kernel<<<dim3(16, 64, 6), 256, 0, stream>>>(W2, w2t,                            2048, 512, (size_t)2048*512, (size_t)512*2048);
  trans_kernel<<<dim3(16, 32, 1), 256, 0, stream>>>(O1, o1t,                            1024, 512, 0, 0);
  trans_kernel<<<dim3(8, 16, 1),  256, 0, stream>>>(O2, o2t,                            512, 256,  0, 0);
  bias_concat_kernel<<<36, 256, 0, stream>>>(bq, bk, bv, bqkv);
  cvt_kernel<<<4096, 256, 0, stream>>>(qe, qx, M * 512 / 8);
  cvt_kernel<<<4096, 256, 0, stream>>>(qa, sA, M * 512 / 8);

  const u16* curB = sA;
  const float* curF = qa;
  const u16* yfin = nullptr;
  const dim3 gA(8, 64);

  for (int li = 0; li < 6; li++) {
    bool ffn  = (li == 0 || li == 1 || li == 3 || li == 5);
    bool excl = (li == 3 || li == 5);
    size_t wqkv_off = (size_t)li * 1536 * 512;

    // fused QKV (non-excl: all three from curB; excl: Q,K from curB, V from yfin)
    gemm256_kernel<false, true><<<dim3(64, 6), 512, 0, stream>>>(
        curB, excl ? yfin : curB, 512, wqkvt + wqkv_off, 512, bqkv + li * 1536,
        qbf, kbf, vbf, 512);

    if (!excl) attn_kernel<true,  false><<<gA, 512, 0, stream>>>(qbf, kbf, vbf, obf, gam, li);
    else       attn_kernel<false, true ><<<gA, 512, 0, stream>>>(qbf, kbf, vbf, obf, gam, li);

    // fused Wo-proj + residual + LN1 -> (g1 fp32, sB bf16)
    gemmln_kernel<true><<<256, 512, 0, stream>>>(
        obf, 512, wot + (size_t)li * 512 * 512, 512, bo + li * 512,
        curF, ln1g + li * 512, ln1b + li * 512, g1, sB);
    curB = sB; curF = g1;

    if (ffn) {
      gemm256_kernel<true, false><<<dim3(64, 8), 512, 0, stream>>>(
          curB, nullptr, 512, w1t + (size_t)li * 2048 * 512, 512, b1 + li * 2048,
          h1, nullptr, nullptr, 2048);
      u16* nB = (li < 2) ? sA : sB;
      // fused W2-proj + residual + LN2; fp32 out dead after li=1 / li=5 -> skip store
      if (li == 1 || li == 5)
        gemmln_kernel<false><<<256, 512, 0, stream>>>(
            h1, 2048, w2t + (size_t)li * 512 * 2048, 2048, b2 + li * 512,
            g1, ln2g + li * 512, ln2b + li * 512, g1, nB);
      else
        gemmln_kernel<true><<<256, 512, 0, stream>>>(
            h1, 2048, w2t + (size_t)li * 512 * 2048, 2048, b2 + li * 512,
            g1, ln2g + li * 512, ln2b + li * 512, g1, nB);
      curB = nB;
    }
    if (li == 1) { yfin = curB; curB = qx; curF = qe; }
  }

  gemm_kernel<true, true, false, false><<<dim3(128, 4), 256, 0, stream>>>(
      curB, qx, 512, 512, 512, o1t, 1024, bO1, nullptr, nullptr, hd1, nullptr, nullptr, 512);
  gemm_kernel<true, true, false, false><<<dim3(128, 2), 256, 0, stream>>>(
      hd1, hd1, BIG, 512, 512, o2t, 512, bO2, nullptr, nullptr, hd2, nullptr, nullptr, 256);
  pred_kernel<<<4096, 256, 0, stream>>>(hd2, O3, bO3, preds);
}